// Round 4
// baseline (162.982 us; speedup 1.0000x reference)
//
#include <hip/hip_runtime.h>
#include <hip/hip_bf16.h>

constexpr int BATCH = 256;
constexpr int VOCAB = 128000;
constexpr int K = 256;
constexpr float IGNORED_C = -3000.0f;

// fast path params
constexpr int NCHUNK = 4;
constexpr int CHUNK = VOCAB / NCHUNK;   // 32000
constexpr int CAP = 512;                // candidate cap == sort width == blockDim

// fallback path params
constexpr int FB_BINS = 8192;
constexpr int FB_SHIFT = 19;
constexpr int FB_CAND = 2048;

// order-preserving f32 -> u32 map (larger float => larger key)
__device__ __forceinline__ unsigned mono(unsigned u) {
    return (u & 0x80000000u) ? ~u : (u | 0x80000000u);
}
__device__ __forceinline__ float inv_mono(unsigned k) {
    unsigned u = (k & 0x80000000u) ? (k ^ 0x80000000u) : ~k;
    return __uint_as_float(u);
}

// ============================================================================
// K1: per (row, chunk) exact top-256 (value desc, idx asc), sorted, u64 keys.
// Selection by sampled threshold + exact count passes (no LDS histogram).
// ============================================================================
__global__ __launch_bounds__(512, 4)
void k1_topk_chunk(const float* __restrict__ logits,
                   unsigned long long* __restrict__ ws_cand)
{
    __shared__ unsigned long long cand[CAP];
    __shared__ unsigned samp[512];
    __shared__ unsigned wred[16];
    __shared__ unsigned ccount;

    const int tid = threadIdx.x;
    const int wave = tid >> 6, lane = tid & 63;
    const int row = blockIdx.x >> 2;            // NCHUNK == 4
    const int chunk = blockIdx.x & 3;
    const int gbase = chunk * CHUNK;
    const float4* rp4 = reinterpret_cast<const float4*>(
        logits + (size_t)row * VOCAB + (size_t)gbase);
    constexpr int N4 = CHUNK / 4;               // 8000

    // ---- load 64 floats/thread, convert to monotone keys (one HBM sweep) ----
    uint4 r[16];
    #pragma unroll
    for (int it = 0; it < 16; ++it) {
        const int i = tid + it * 512;
        if (it < 15 || tid < (N4 - 15 * 512)) {
            float4 f = rp4[i];
            r[it] = make_uint4(mono(__float_as_uint(f.x)), mono(__float_as_uint(f.y)),
                               mono(__float_as_uint(f.z)), mono(__float_as_uint(f.w)));
        } else {
            r[it] = make_uint4(0u, 0u, 0u, 0u);   // never read
        }
    }

    // ---- exact count pass: ngt = #(key > T), neq = #(key == T && loc <= tieX) ----
    auto count_pass = [&](unsigned T, unsigned tieX, unsigned &ngt, unsigned &neq) {
        unsigned cgt = 0, ceq = 0;
        #pragma unroll
        for (int it = 0; it < 16; ++it) {
            if (it == 15 && tid >= (N4 - 15 * 512)) continue;
            const unsigned base = 4u * (unsigned)(tid + it * 512);
            const uint4 q = r[it];
            cgt += (q.x > T); ceq += (q.x == T && (base + 0u) <= tieX);
            cgt += (q.y > T); ceq += (q.y == T && (base + 1u) <= tieX);
            cgt += (q.z > T); ceq += (q.z == T && (base + 2u) <= tieX);
            cgt += (q.w > T); ceq += (q.w == T && (base + 3u) <= tieX);
        }
        #pragma unroll
        for (int off = 32; off >= 1; off >>= 1) {
            cgt += __shfl_xor(cgt, off);
            ceq += __shfl_xor(ceq, off);
        }
        __syncthreads();                 // protect wred reuse across passes
        if (lane == 0) { wred[wave] = cgt; wred[8 + wave] = ceq; }
        __syncthreads();
        unsigned g = 0, e = 0;
        #pragma unroll
        for (int w2 = 0; w2 < 8; ++w2) { g += wred[w2]; e += wred[8 + w2]; }
        ngt = g; neq = e;
    };

    // ---- sample: one key per thread, spread across chunk quarters ----
    {
        const int j2 = tid & 3, c = (tid >> 2) & 3;
        uint4 f = r[0];
        if (j2 == 1) f = r[4];
        if (j2 == 2) f = r[8];
        if (j2 == 3) f = r[12];
        unsigned sv = f.x;
        if (c == 1) sv = f.y;
        if (c == 2) sv = f.z;
        if (c == 3) sv = f.w;

        // hybrid bitonic sort 512 samples, descending (shfl j<64, LDS j>=64)
        unsigned v = sv;
        #pragma unroll
        for (int kk = 2; kk <= 512; kk <<= 1) {
            for (int j = kk >> 1; j > 0; j >>= 1) {
                const bool keepMax = (((tid & kk) == 0) == ((tid & j) == 0));
                unsigned w;
                if (j >= 64) {
                    __syncthreads();
                    samp[tid] = v;
                    __syncthreads();
                    w = samp[tid ^ j];
                } else {
                    w = __shfl_xor(v, j);
                }
                v = keepMax ? (v >= w ? v : w) : (v <= w ? v : w);
            }
        }
        __syncthreads();
        samp[tid] = v;                   // sorted descending
        __syncthreads();
    }

    // ---- threshold: T = samp[5] (expected count ~375), verify exactly ----
    unsigned T = samp[5];
    unsigned ngt, neq;
    count_pass(T, 0xFFFFFFFFu, ngt, neq);
    unsigned nge = ngt + neq;

    if (nge < (unsigned)K || nge > (unsigned)CAP) {
        // rank-space binary search: smallest r with n_ge(samp[r]) >= K
        int lo = -1, hi = 511;           // samp[511] qualifies (samples subset)
        while (hi - lo > 1) {
            const int mid = (lo + hi) >> 1;
            count_pass(samp[mid], 0xFFFFFFFFu, ngt, neq);
            if (ngt + neq >= (unsigned)K) hi = mid; else lo = mid;
        }
        T = samp[hi];
        count_pass(T, 0xFFFFFFFFu, ngt, neq);
        nge = ngt + neq;
        if (nge > (unsigned)CAP) {
            // key-space: largest T0 with n_ge(T0) >= K in (samp[hi], khi]
            unsigned klo = T;
            unsigned khi = (hi > 0) ? samp[hi - 1] : 0xFFFFFFFFu;
            count_pass(khi, 0xFFFFFFFFu, ngt, neq);
            if (ngt + neq >= (unsigned)K) {
                klo = khi;
            } else {
                while (khi - klo > 1) {
                    const unsigned kmid = klo + ((khi - klo) >> 1);
                    count_pass(kmid, 0xFFFFFFFFu, ngt, neq);
                    if (ngt + neq >= (unsigned)K) klo = kmid; else khi = kmid;
                }
            }
            T = klo;
            count_pass(T, 0xFFFFFFFFu, ngt, neq);
            nge = ngt + neq;
        }
    }

    // ---- tie path (pathological duplicates): pick K-ngt smallest indices at T ----
    bool tie = false;
    unsigned X = 0xFFFFFFFFu;
    if (nge > (unsigned)CAP) {
        tie = true;
        const unsigned target = (unsigned)K - ngt;     // ngt < K by maximality of T
        int xlo = -1, xhi = CHUNK - 1;
        while (xhi - xlo > 1) {
            const int xmid = (xlo + xhi) >> 1;
            unsigned g2, e2;
            count_pass(T, (unsigned)xmid, g2, e2);
            if (e2 >= target) xhi = xmid; else xlo = xmid;
        }
        X = (unsigned)xhi;
    }

    // ---- collect candidates from registers ----
    if (tid == 0) ccount = 0u;
    __syncthreads();
    #pragma unroll
    for (int it = 0; it < 16; ++it) {
        if (it == 15 && tid >= (N4 - 15 * 512)) continue;
        const unsigned base = 4u * (unsigned)(tid + it * 512);
        const uint4 q = r[it];
        #pragma unroll
        for (int c = 0; c < 4; ++c) {
            const unsigned k2 = (c == 0) ? q.x : (c == 1) ? q.y : (c == 2) ? q.z : q.w;
            const unsigned loc = base + (unsigned)c;
            const bool sel = (k2 > T) || (k2 == T && (!tie || loc <= X));
            if (sel) {
                const unsigned p = atomicAdd(&ccount, 1u);
                if (p < (unsigned)CAP)
                    cand[p] = ((unsigned long long)k2 << 32) | (unsigned)(~(gbase + (int)loc));
            }
        }
    }
    __syncthreads();
    const unsigned cc = ccount;
    if ((unsigned)tid >= cc) cand[tid] = 0ull;   // pad (always < any candidate)
    __syncthreads();

    // ---- hybrid bitonic sort 512 candidates (u64), descending ----
    unsigned long long v = cand[tid];
    #pragma unroll
    for (int kk = 2; kk <= CAP; kk <<= 1) {
        for (int j = kk >> 1; j > 0; j >>= 1) {
            const bool keepMax = (((tid & kk) == 0) == ((tid & j) == 0));
            unsigned long long w;
            if (j >= 64) {
                __syncthreads();
                cand[tid] = v;
                __syncthreads();
                w = cand[tid ^ j];
            } else {
                w = __shfl_xor(v, j);
            }
            v = keepMax ? (v >= w ? v : w) : (v <= w ? v : w);
        }
    }

    if (tid < K) ws_cand[(size_t)blockIdx.x * K + tid] = v;
}

// ============================================================================
// K2: per row partial top-256 merge of 4 sorted runs + softmax/cumsum pipeline
// ============================================================================
__global__ __launch_bounds__(512)
void k2_merge(const float* __restrict__ params,
              const unsigned long long* __restrict__ ws_cand,
              float* __restrict__ ws_v, float* __restrict__ ws_csum,
              int* __restrict__ ws_idx, float* __restrict__ ws_p0)
{
    constexpr int N = NCHUNK * K;   // 1024
    __shared__ unsigned long long lds[N];
    __shared__ float red[K];
    __shared__ float sc[K];

    const int row = blockIdx.x;
    const int tid = threadIdx.x;

    lds[tid]       = ws_cand[(size_t)row * N + tid];
    lds[tid + 512] = ws_cand[(size_t)row * N + tid + 512];
    __syncthreads();

    // level 1: top-256 of (run0,run1) and (run2,run3) via bitonic partial merge
    // thread t: p = t>>8, s = t&255 -> max(run(2p)[s], run(2p+1)[255-s])
    unsigned long long v;
    {
        const int p = tid >> 8, s = tid & 255;
        const unsigned long long a = lds[p * 512 + s];
        const unsigned long long b = lds[p * 512 + 511 - s];
        v = (a >= b) ? a : b;
    }
    // clean the two bitonic-256 sequences, descending
    #pragma unroll
    for (int j = 128; j >= 64; j >>= 1) {
        __syncthreads();
        lds[tid] = v;
        __syncthreads();
        const unsigned long long w = lds[tid ^ j];
        v = ((tid & j) == 0) ? (v >= w ? v : w) : (v <= w ? v : w);
    }
    #pragma unroll
    for (int j = 32; j >= 1; j >>= 1) {
        const unsigned long long w = __shfl_xor(v, j);
        v = ((tid & j) == 0) ? (v >= w ? v : w) : (v <= w ? v : w);
    }

    // level 2: top-256 of (M0, M1)
    __syncthreads();
    lds[tid] = v;
    __syncthreads();
    if (tid < K) {
        const unsigned long long a = lds[tid];
        const unsigned long long b = lds[511 - tid];
        v = (a >= b) ? a : b;
    }
    #pragma unroll
    for (int j = 128; j >= 64; j >>= 1) {
        __syncthreads();
        if (tid < K) lds[tid] = v;
        __syncthreads();
        if (tid < K) {
            const unsigned long long w = lds[tid ^ j];
            v = ((tid & j) == 0) ? (v >= w ? v : w) : (v <= w ? v : w);
        }
    }
    if (tid < K) {
        #pragma unroll
        for (int j = 32; j >= 1; j >>= 1) {
            const unsigned long long w = __shfl_xor(v, j);
            v = ((tid & j) == 0) ? (v >= w ? v : w) : (v <= w ? v : w);
        }
    }

    // pipeline on sorted top-256: topk-mask -> /temp -> softmax -> cumsum
    const bool act = tid < K;
    const float topk_f = params[row * 3 + 0];
    const float temp   = params[row * 3 + 2];
    float vv = 0.f;
    int myidx = 0;
    if (act) {
        const float val = inv_mono((unsigned)(v >> 32));
        myidx = (int)(~(unsigned)v);
        const float x = (((float)tid) >= topk_f) ? IGNORED_C : val;
        vv = x / temp;
        red[tid] = vv;
    }
    __syncthreads();
    for (int s = K / 2; s > 0; s >>= 1) {
        if (tid < s) red[tid] = fmaxf(red[tid], red[tid + s]);
        __syncthreads();
    }
    const float m = red[0];
    __syncthreads();
    const float e = act ? expf(vv - m) : 0.f;
    if (act) red[tid] = e;
    __syncthreads();
    for (int s = K / 2; s > 0; s >>= 1) {
        if (tid < s) red[tid] += red[tid + s];
        __syncthreads();
    }
    const float ssum = red[0];
    __syncthreads();
    const float p = e / ssum;
    if (act) sc[tid] = p;
    __syncthreads();
    for (int off = 1; off < K; off <<= 1) {
        float t = 0.f;
        if (act && tid >= off) t = sc[tid - off];
        __syncthreads();
        if (act) sc[tid] += t;
        __syncthreads();
    }
    if (act) {
        ws_v[row * K + tid]    = vv;
        ws_csum[row * K + tid] = sc[tid];
        ws_idx[row * K + tid]  = myidx;
    }
    if (tid == 0) ws_p0[row] = p;   // probs[0] == csum[0]
}

// ============================================================================
// K3: global-min(p0) -> top-p mask -> softmax -> cumsum -> sample
// ============================================================================
__global__ __launch_bounds__(K)
void k3_sample(const float* __restrict__ params,
               const float* __restrict__ rand_u,
               const float* __restrict__ ws_v,
               const float* __restrict__ ws_csum,
               const int* __restrict__ ws_idx,
               const float* __restrict__ ws_p0,
               int* __restrict__ out)
{
    __shared__ float red[K];
    __shared__ float sc[K];
    const int row = blockIdx.x;
    const int tid = threadIdx.x;

    red[tid] = ws_p0[tid];          // BATCH == 256 == blockDim
    __syncthreads();
    for (int s = K / 2; s > 0; s >>= 1) {
        if (tid < s) red[tid] = fminf(red[tid], red[tid + s]);
        __syncthreads();
    }
    const float tpe = fmaxf(red[0], params[row * 3 + 1]);
    __syncthreads();

    const float csum = ws_csum[row * K + tid];
    const float v0   = ws_v[row * K + tid];
    const float v2 = ((csum > tpe) && (tid != 0)) ? IGNORED_C : v0;
    red[tid] = v2;
    __syncthreads();
    for (int s = K / 2; s > 0; s >>= 1) {
        if (tid < s) red[tid] = fmaxf(red[tid], red[tid + s]);
        __syncthreads();
    }
    const float m = red[0];
    __syncthreads();
    const float e = expf(v2 - m);
    red[tid] = e;
    __syncthreads();
    for (int s = K / 2; s > 0; s >>= 1) {
        if (tid < s) red[tid] += red[tid + s];
        __syncthreads();
    }
    const float ssum = red[0];
    __syncthreads();
    const float p = e / ssum;
    sc[tid] = p;
    __syncthreads();
    for (int off = 1; off < K; off <<= 1) {
        float t = (tid >= off) ? sc[tid - off] : 0.f;
        __syncthreads();
        sc[tid] += t;
        __syncthreads();
    }
    const float ru = rand_u[row];
    red[tid] = (ru > sc[tid]) ? 1.f : 0.f;
    __syncthreads();
    for (int s = K / 2; s > 0; s >>= 1) {
        if (tid < s) red[tid] += red[tid + s];
        __syncthreads();
    }
    if (tid == 0) {
        int sel = (int)red[0];
        if (sel > K - 1) sel = K - 1;
        out[row] = ws_idx[row * K + sel];
    }
}

// ============================================================================
// Fallback (round-1 proven): single block per row, used only if ws too small
// ============================================================================
__global__ __launch_bounds__(1024)
void fb_stage1(const float* __restrict__ logits,
               const float* __restrict__ params,
               float* __restrict__ ws_v,
               float* __restrict__ ws_csum,
               int* __restrict__ ws_idx,
               float* __restrict__ ws_p0)
{
    __shared__ unsigned hist[FB_BINS];
    __shared__ unsigned gsum[128];
    __shared__ unsigned long long cand[FB_CAND];
    __shared__ unsigned ccount;
    __shared__ int tbin;
    __shared__ float sv[K];
    __shared__ float se[K];
    __shared__ int   sidx[K];
    __shared__ float sred;

    const int row = blockIdx.x;
    const int tid = threadIdx.x;
    const float4* rp4 = reinterpret_cast<const float4*>(logits + (size_t)row * VOCAB);

    for (int i = tid; i < FB_BINS; i += 1024) hist[i] = 0u;
    __syncthreads();
    for (int i = tid; i < VOCAB / 4; i += 1024) {
        float4 v = rp4[i];
        atomicAdd(&hist[mono(__float_as_uint(v.x)) >> FB_SHIFT], 1u);
        atomicAdd(&hist[mono(__float_as_uint(v.y)) >> FB_SHIFT], 1u);
        atomicAdd(&hist[mono(__float_as_uint(v.z)) >> FB_SHIFT], 1u);
        atomicAdd(&hist[mono(__float_as_uint(v.w)) >> FB_SHIFT], 1u);
    }
    __syncthreads();
    if (tid < 128) {
        unsigned s = 0;
        for (int i = 0; i < 64; ++i) s += hist[tid * 64 + i];
        gsum[tid] = s;
    }
    __syncthreads();
    if (tid == 0) {
        unsigned acc = 0;
        int g = 127;
        for (; g > 0; --g) {
            if (acc + gsum[g] >= (unsigned)K) break;
            acc += gsum[g];
        }
        int t = g * 64;
        for (int bin = g * 64 + 63; bin >= g * 64; --bin) {
            acc += hist[bin];
            if (acc >= (unsigned)K) { t = bin; break; }
        }
        tbin = t;
        ccount = 0u;
    }
    __syncthreads();
    const unsigned tb = (unsigned)tbin;
    for (int i = tid; i < VOCAB / 4; i += 1024) {
        float4 v = rp4[i];
        const int base = i * 4;
        unsigned kk[4] = { mono(__float_as_uint(v.x)), mono(__float_as_uint(v.y)),
                           mono(__float_as_uint(v.z)), mono(__float_as_uint(v.w)) };
        #pragma unroll
        for (int c = 0; c < 4; ++c) {
            if ((kk[c] >> FB_SHIFT) >= tb) {
                unsigned p = atomicAdd(&ccount, 1u);
                if (p < FB_CAND)
                    cand[p] = ((unsigned long long)kk[c] << 32) | (unsigned)(~(base + c));
            }
        }
    }
    __syncthreads();
    for (int i = tid; i < FB_CAND; i += 1024)
        if ((unsigned)i >= ccount) cand[i] = 0ull;
    __syncthreads();
    for (int k = 2; k <= FB_CAND; k <<= 1) {
        for (int j = k >> 1; j > 0; j >>= 1) {
            for (int i = tid; i < FB_CAND; i += 1024) {
                int ixj = i ^ j;
                if (ixj > i) {
                    unsigned long long a = cand[i], b = cand[ixj];
                    bool sw = ((i & k) == 0) ? (a < b) : (a > b);
                    if (sw) { cand[i] = b; cand[ixj] = a; }
                }
            }
            __syncthreads();
        }
    }
    const float topk_f = params[row * 3 + 0];
    const float temp   = params[row * 3 + 2];
    if (tid < K) {
        unsigned long long c = cand[tid];
        float val = inv_mono((unsigned)(c >> 32));
        sidx[tid] = (int)(~(unsigned)c);
        float v = (((float)tid) >= topk_f) ? IGNORED_C : val;
        sv[tid] = v / temp;
    }
    __syncthreads();
    if (tid == 0) {
        float mm = sv[0];
        for (int i = 1; i < K; ++i) mm = fmaxf(mm, sv[i]);
        sred = mm;
    }
    __syncthreads();
    if (tid < K) se[tid] = expf(sv[tid] - sred);
    __syncthreads();
    if (tid == 0) {
        float s = 0.f;
        for (int i = 0; i < K; ++i) s += se[i];
        sred = s;
    }
    __syncthreads();
    if (tid < K) se[tid] = se[tid] / sred;
    __syncthreads();
    if (tid == 0) {
        float c = 0.f;
        for (int i = 0; i < K; ++i) { c += se[i]; se[i] = c; }
    }
    __syncthreads();
    if (tid < K) {
        ws_v[row * K + tid]    = sv[tid];
        ws_csum[row * K + tid] = se[tid];
        ws_idx[row * K + tid]  = sidx[tid];
    }
    if (tid == 0) ws_p0[row] = se[0];
}

extern "C" void kernel_launch(void* const* d_in, const int* in_sizes, int n_in,
                              void* d_out, int out_size, void* d_ws, size_t ws_size,
                              hipStream_t stream) {
    const float* logits = (const float*)d_in[0];
    const float* params = (const float*)d_in[1];
    const float* randu  = (const float*)d_in[2];
    int* out = (int*)d_out;
    char* ws = (char*)d_ws;

    const size_t cand_bytes = (size_t)BATCH * NCHUNK * K * 8;          // 2 MB
    const size_t tail_bytes = (size_t)3 * BATCH * K * 4 + BATCH * 4;   // 769 KB
    if (ws_size >= cand_bytes + tail_bytes) {
        unsigned long long* ws_cand = (unsigned long long*)ws;
        char* p = ws + cand_bytes;
        float* ws_v    = (float*)(p);
        float* ws_csum = (float*)(p + (size_t)BATCH * K * 4);
        int*   ws_idx  = (int*)  (p + (size_t)2 * BATCH * K * 4);
        float* ws_p0   = (float*)(p + (size_t)3 * BATCH * K * 4);
        hipLaunchKernelGGL(k1_topk_chunk, dim3(BATCH * NCHUNK), dim3(512), 0, stream,
                           logits, ws_cand);
        hipLaunchKernelGGL(k2_merge, dim3(BATCH), dim3(512), 0, stream,
                           params, ws_cand, ws_v, ws_csum, ws_idx, ws_p0);
        hipLaunchKernelGGL(k3_sample, dim3(BATCH), dim3(K), 0, stream,
                           params, randu, ws_v, ws_csum, ws_idx, ws_p0, out);
    } else {
        float* ws_v    = (float*)(ws);
        float* ws_csum = (float*)(ws + (size_t)BATCH * K * 4);
        int*   ws_idx  = (int*)  (ws + (size_t)2 * BATCH * K * 4);
        float* ws_p0   = (float*)(ws + (size_t)3 * BATCH * K * 4);
        hipLaunchKernelGGL(fb_stage1, dim3(BATCH), dim3(1024), 0, stream,
                           logits, params, ws_v, ws_csum, ws_idx, ws_p0);
        hipLaunchKernelGGL(k3_sample, dim3(BATCH), dim3(K), 0, stream,
                           params, randu, ws_v, ws_csum, ws_idx, ws_p0, out);
    }
}

// Round 5
// 127.500 us; speedup vs baseline: 1.2783x; 1.2783x over previous
//
#include <hip/hip_runtime.h>
#include <hip/hip_bf16.h>

constexpr int BATCH = 256;
constexpr int VOCAB = 128000;
constexpr int K = 256;
constexpr float IGNORED_C = -3000.0f;

// fast path params
constexpr int NCHUNK = 8;
constexpr int CHUNK = VOCAB / NCHUNK;   // 16000
constexpr int CAP = 512;                // candidate cap == sort width == blockDim
constexpr int N4 = CHUNK / 4;           // 4000 float4 per chunk
constexpr int TAIL = N4 - 7 * 512;      // 416: threads with it==7 valid

// fallback path params
constexpr int FB_BINS = 8192;
constexpr int FB_SHIFT = 19;
constexpr int FB_CAND = 2048;

// order-preserving f32 -> u32 map (larger float => larger key)
__device__ __forceinline__ unsigned mono(unsigned u) {
    return (u & 0x80000000u) ? ~u : (u | 0x80000000u);
}
__device__ __forceinline__ float inv_mono(unsigned k) {
    unsigned u = (k & 0x80000000u) ? (k ^ 0x80000000u) : ~k;
    return __uint_as_float(u);
}

// ============================================================================
// K1: per (row, chunk) exact top-256 (value desc, idx asc), sorted, u64 keys.
// Selection: sampled threshold + exact register count passes. 32 VGPRs of
// data per thread (8 x uint4) -- the round-4 spill came from 64.
// ============================================================================
__global__ __launch_bounds__(512, 8)
void k1_topk_chunk(const float* __restrict__ logits,
                   unsigned long long* __restrict__ ws_cand)
{
    __shared__ unsigned long long cand[CAP];
    __shared__ unsigned samp[512];
    __shared__ unsigned wred[16];
    __shared__ unsigned ccount;

    const int tid = threadIdx.x;
    const int wave = tid >> 6, lane = tid & 63;
    const int row = blockIdx.x >> 3;            // NCHUNK == 8
    const int chunk = blockIdx.x & 7;
    const int gbase = chunk * CHUNK;
    const float4* rp4 = reinterpret_cast<const float4*>(
        logits + (size_t)row * VOCAB + (size_t)gbase);

    // ---- load ~31 floats/thread as monotone keys (one HBM sweep) ----
    uint4 r[8];
    #pragma unroll
    for (int it = 0; it < 8; ++it) {
        const int i = tid + it * 512;
        if (it < 7 || tid < TAIL) {
            float4 f = rp4[i];
            r[it] = make_uint4(mono(__float_as_uint(f.x)), mono(__float_as_uint(f.y)),
                               mono(__float_as_uint(f.z)), mono(__float_as_uint(f.w)));
        } else {
            r[it] = make_uint4(0u, 0u, 0u, 0u);   // never counted (guarded)
        }
    }

    // ---- exact count pass over registers ----
    auto count_pass = [&](unsigned T, unsigned tieX, unsigned &ngt, unsigned &neq) {
        unsigned cgt = 0, ceq = 0;
        #pragma unroll
        for (int it = 0; it < 8; ++it) {
            if (it == 7 && tid >= TAIL) continue;
            const unsigned base = 4u * (unsigned)(tid + it * 512);
            const uint4 q = r[it];
            cgt += (q.x > T); ceq += (q.x == T && (base + 0u) <= tieX);
            cgt += (q.y > T); ceq += (q.y == T && (base + 1u) <= tieX);
            cgt += (q.z > T); ceq += (q.z == T && (base + 2u) <= tieX);
            cgt += (q.w > T); ceq += (q.w == T && (base + 3u) <= tieX);
        }
        #pragma unroll
        for (int off = 32; off >= 1; off >>= 1) {
            cgt += __shfl_xor(cgt, off);
            ceq += __shfl_xor(ceq, off);
        }
        __syncthreads();                 // protect wred reuse across passes
        if (lane == 0) { wred[wave] = cgt; wred[8 + wave] = ceq; }
        __syncthreads();
        unsigned g = 0, e = 0;
        #pragma unroll
        for (int w2 = 0; w2 < 8; ++w2) { g += wred[w2]; e += wred[8 + w2]; }
        ngt = g; neq = e;
    };

    // ---- sample: one key per thread (first quarter of chunk), sort desc ----
    {
        const int j2 = tid & 3, c = (tid >> 2) & 3;
        uint4 f = r[0];
        if (j2 == 1) f = r[1];
        if (j2 == 2) f = r[2];
        if (j2 == 3) f = r[3];
        unsigned sv = f.x;
        if (c == 1) sv = f.y;
        if (c == 2) sv = f.z;
        if (c == 3) sv = f.w;

        unsigned v = sv;
        #pragma unroll
        for (int kk = 2; kk <= 512; kk <<= 1) {
            for (int j = kk >> 1; j > 0; j >>= 1) {
                const bool keepMax = (((tid & kk) == 0) == ((tid & j) == 0));
                unsigned w;
                if (j >= 64) {
                    __syncthreads();
                    samp[tid] = v;
                    __syncthreads();
                    w = samp[tid ^ j];
                } else {
                    w = __shfl_xor(v, j);
                }
                v = keepMax ? (v >= w ? v : w) : (v <= w ? v : w);
            }
        }
        __syncthreads();
        samp[tid] = v;                   // sorted descending
        __syncthreads();
    }

    // ---- threshold: T = samp[11] (expected count ~375), verify exactly ----
    unsigned T = samp[11];
    unsigned ngt, neq;
    count_pass(T, 0xFFFFFFFFu, ngt, neq);
    unsigned nge = ngt + neq;

    if (nge < (unsigned)K || nge > (unsigned)CAP) {
        // rank-space binary search: smallest r with n_ge(samp[r]) >= K
        int lo, hi;
        if (nge < (unsigned)K) { lo = 11; hi = 511; }   // samp[511]: count>=512>=K
        else                   { lo = -1; hi = 11;  }   // samp[11] already >= K
        while (hi - lo > 1) {
            const int mid = (lo + hi) >> 1;
            count_pass(samp[mid], 0xFFFFFFFFu, ngt, neq);
            if (ngt + neq >= (unsigned)K) hi = mid; else lo = mid;
        }
        T = samp[hi];
        count_pass(T, 0xFFFFFFFFu, ngt, neq);
        nge = ngt + neq;
        if (nge > (unsigned)CAP) {
            // key-space: largest T0 with n_ge(T0) >= K in (samp[hi], khi]
            unsigned klo = T;
            unsigned khi = (hi > 0) ? samp[hi - 1] : 0xFFFFFFFFu;
            count_pass(khi, 0xFFFFFFFFu, ngt, neq);
            if (ngt + neq >= (unsigned)K) {
                klo = khi;
            } else {
                while (khi - klo > 1) {
                    const unsigned kmid = klo + ((khi - klo) >> 1);
                    count_pass(kmid, 0xFFFFFFFFu, ngt, neq);
                    if (ngt + neq >= (unsigned)K) klo = kmid; else khi = kmid;
                }
            }
            T = klo;
            count_pass(T, 0xFFFFFFFFu, ngt, neq);
            nge = ngt + neq;
        }
    }

    // ---- tie path (pathological duplicates): pick K-ngt smallest indices at T ----
    bool tie = false;
    unsigned X = 0xFFFFFFFFu;
    if (nge > (unsigned)CAP) {
        tie = true;
        const unsigned target = (unsigned)K - ngt;     // ngt < K by maximality of T
        int xlo = -1, xhi = CHUNK - 1;
        while (xhi - xlo > 1) {
            const int xmid = (xlo + xhi) >> 1;
            unsigned g2, e2;
            count_pass(T, (unsigned)xmid, g2, e2);
            if (e2 >= target) xhi = xmid; else xlo = xmid;
        }
        X = (unsigned)xhi;
    }

    // ---- collect candidates from registers ----
    if (tid == 0) ccount = 0u;
    __syncthreads();
    #pragma unroll
    for (int it = 0; it < 8; ++it) {
        if (it == 7 && tid >= TAIL) continue;
        const unsigned base = 4u * (unsigned)(tid + it * 512);
        const uint4 q = r[it];
        #pragma unroll
        for (int c = 0; c < 4; ++c) {
            const unsigned k2 = (c == 0) ? q.x : (c == 1) ? q.y : (c == 2) ? q.z : q.w;
            const unsigned loc = base + (unsigned)c;
            const bool sel = (k2 > T) || (k2 == T && (!tie || loc <= X));
            if (sel) {
                const unsigned p = atomicAdd(&ccount, 1u);
                if (p < (unsigned)CAP)
                    cand[p] = ((unsigned long long)k2 << 32) | (unsigned)(~(gbase + (int)loc));
            }
        }
    }
    __syncthreads();
    const unsigned cc = ccount;
    if ((unsigned)tid >= cc) cand[tid] = 0ull;   // pad (always < any candidate)
    __syncthreads();

    // ---- hybrid bitonic sort 512 candidates (u64), descending ----
    unsigned long long v = cand[tid];
    #pragma unroll
    for (int kk = 2; kk <= CAP; kk <<= 1) {
        for (int j = kk >> 1; j > 0; j >>= 1) {
            const bool keepMax = (((tid & kk) == 0) == ((tid & j) == 0));
            unsigned long long w;
            if (j >= 64) {
                __syncthreads();
                cand[tid] = v;
                __syncthreads();
                w = cand[tid ^ j];
            } else {
                w = __shfl_xor(v, j);
            }
            v = keepMax ? (v >= w ? v : w) : (v <= w ? v : w);
        }
    }

    if (tid < K) ws_cand[(size_t)blockIdx.x * K + tid] = v;
}

// ============================================================================
// K2: per row merge 8 sorted runs (bitonic merge stages only) + pipeline
// ============================================================================
__global__ __launch_bounds__(1024)
void k2_merge(const float* __restrict__ params,
              const unsigned long long* __restrict__ ws_cand,
              float* __restrict__ ws_v, float* __restrict__ ws_csum,
              int* __restrict__ ws_idx, float* __restrict__ ws_p0)
{
    constexpr int N = NCHUNK * K;   // 2048
    __shared__ unsigned long long cand[N];
    __shared__ float red[K];
    __shared__ float sc[K];

    const int row = blockIdx.x;
    const int tid = threadIdx.x;

    // load; reverse odd runs so runs alternate desc/asc (valid bitonic state k=256)
    for (int i = tid; i < N; i += 1024) {
        const int c = i >> 8, pos = i & (K - 1);
        unsigned long long v = ws_cand[(size_t)row * N + i];
        const int dest = (c & 1) ? ((c << 8) | (K - 1 - pos)) : i;
        cand[dest] = v;
    }
    __syncthreads();

    // bitonic merge stages k = 512, 1024, 2048 (descending overall)
    for (int kk2 = 2 * K; kk2 <= N; kk2 <<= 1) {
        for (int j = kk2 >> 1; j > 0; j >>= 1) {
            for (int i = tid; i < N; i += 1024) {
                const int ixj = i ^ j;
                if (ixj > i) {
                    unsigned long long a = cand[i], b = cand[ixj];
                    bool sw = ((i & kk2) == 0) ? (a < b) : (a > b);
                    if (sw) { cand[i] = b; cand[ixj] = a; }
                }
            }
            __syncthreads();
        }
    }

    // pipeline on top-256: topk-mask -> /temp -> softmax -> cumsum
    const bool act = tid < K;
    const float topk_f = params[row * 3 + 0];
    const float temp   = params[row * 3 + 2];
    float v = 0.f;
    int myidx = 0;
    if (act) {
        unsigned long long c = cand[tid];
        float val = inv_mono((unsigned)(c >> 32));
        myidx = (int)(~(unsigned)c);
        float x = (((float)tid) >= topk_f) ? IGNORED_C : val;
        v = x / temp;
        red[tid] = v;
    }
    __syncthreads();
    for (int s = K / 2; s > 0; s >>= 1) {
        if (tid < s) red[tid] = fmaxf(red[tid], red[tid + s]);
        __syncthreads();
    }
    const float m = red[0];
    __syncthreads();
    const float e = act ? expf(v - m) : 0.f;
    if (act) red[tid] = e;
    __syncthreads();
    for (int s = K / 2; s > 0; s >>= 1) {
        if (tid < s) red[tid] += red[tid + s];
        __syncthreads();
    }
    const float ssum = red[0];
    __syncthreads();
    const float p = e / ssum;
    if (act) sc[tid] = p;
    __syncthreads();
    for (int off = 1; off < K; off <<= 1) {
        float t = 0.f;
        if (act && tid >= off) t = sc[tid - off];
        __syncthreads();
        if (act) sc[tid] += t;
        __syncthreads();
    }
    if (act) {
        ws_v[row * K + tid]    = v;
        ws_csum[row * K + tid] = sc[tid];
        ws_idx[row * K + tid]  = myidx;
    }
    if (tid == 0) ws_p0[row] = p;   // probs[0] == csum[0]
}

// ============================================================================
// K3: global-min(p0) -> top-p mask -> softmax -> cumsum -> sample
// ============================================================================
__global__ __launch_bounds__(K)
void k3_sample(const float* __restrict__ params,
               const float* __restrict__ rand_u,
               const float* __restrict__ ws_v,
               const float* __restrict__ ws_csum,
               const int* __restrict__ ws_idx,
               const float* __restrict__ ws_p0,
               int* __restrict__ out)
{
    __shared__ float red[K];
    __shared__ float sc[K];
    const int row = blockIdx.x;
    const int tid = threadIdx.x;

    red[tid] = ws_p0[tid];          // BATCH == 256 == blockDim
    __syncthreads();
    for (int s = K / 2; s > 0; s >>= 1) {
        if (tid < s) red[tid] = fminf(red[tid], red[tid + s]);
        __syncthreads();
    }
    const float tpe = fmaxf(red[0], params[row * 3 + 1]);
    __syncthreads();

    const float csum = ws_csum[row * K + tid];
    const float v0   = ws_v[row * K + tid];
    const float v2 = ((csum > tpe) && (tid != 0)) ? IGNORED_C : v0;
    red[tid] = v2;
    __syncthreads();
    for (int s = K / 2; s > 0; s >>= 1) {
        if (tid < s) red[tid] = fmaxf(red[tid], red[tid + s]);
        __syncthreads();
    }
    const float m = red[0];
    __syncthreads();
    const float e = expf(v2 - m);
    red[tid] = e;
    __syncthreads();
    for (int s = K / 2; s > 0; s >>= 1) {
        if (tid < s) red[tid] += red[tid + s];
        __syncthreads();
    }
    const float ssum = red[0];
    __syncthreads();
    const float p = e / ssum;
    sc[tid] = p;
    __syncthreads();
    for (int off = 1; off < K; off <<= 1) {
        float t = (tid >= off) ? sc[tid - off] : 0.f;
        __syncthreads();
        sc[tid] += t;
        __syncthreads();
    }
    const float ru = rand_u[row];
    red[tid] = (ru > sc[tid]) ? 1.f : 0.f;
    __syncthreads();
    for (int s = K / 2; s > 0; s >>= 1) {
        if (tid < s) red[tid] += red[tid + s];
        __syncthreads();
    }
    if (tid == 0) {
        int sel = (int)red[0];
        if (sel > K - 1) sel = K - 1;
        out[row] = ws_idx[row * K + sel];
    }
}

// ============================================================================
// Fallback (round-1 proven): single block per row, used only if ws too small
// ============================================================================
__global__ __launch_bounds__(1024)
void fb_stage1(const float* __restrict__ logits,
               const float* __restrict__ params,
               float* __restrict__ ws_v,
               float* __restrict__ ws_csum,
               int* __restrict__ ws_idx,
               float* __restrict__ ws_p0)
{
    __shared__ unsigned hist[FB_BINS];
    __shared__ unsigned gsum[128];
    __shared__ unsigned long long cand[FB_CAND];
    __shared__ unsigned ccount;
    __shared__ int tbin;
    __shared__ float sv[K];
    __shared__ float se[K];
    __shared__ int   sidx[K];
    __shared__ float sred;

    const int row = blockIdx.x;
    const int tid = threadIdx.x;
    const float4* rp4 = reinterpret_cast<const float4*>(logits + (size_t)row * VOCAB);

    for (int i = tid; i < FB_BINS; i += 1024) hist[i] = 0u;
    __syncthreads();
    for (int i = tid; i < VOCAB / 4; i += 1024) {
        float4 v = rp4[i];
        atomicAdd(&hist[mono(__float_as_uint(v.x)) >> FB_SHIFT], 1u);
        atomicAdd(&hist[mono(__float_as_uint(v.y)) >> FB_SHIFT], 1u);
        atomicAdd(&hist[mono(__float_as_uint(v.z)) >> FB_SHIFT], 1u);
        atomicAdd(&hist[mono(__float_as_uint(v.w)) >> FB_SHIFT], 1u);
    }
    __syncthreads();
    if (tid < 128) {
        unsigned s = 0;
        for (int i = 0; i < 64; ++i) s += hist[tid * 64 + i];
        gsum[tid] = s;
    }
    __syncthreads();
    if (tid == 0) {
        unsigned acc = 0;
        int g = 127;
        for (; g > 0; --g) {
            if (acc + gsum[g] >= (unsigned)K) break;
            acc += gsum[g];
        }
        int t = g * 64;
        for (int bin = g * 64 + 63; bin >= g * 64; --bin) {
            acc += hist[bin];
            if (acc >= (unsigned)K) { t = bin; break; }
        }
        tbin = t;
        ccount = 0u;
    }
    __syncthreads();
    const unsigned tb = (unsigned)tbin;
    for (int i = tid; i < VOCAB / 4; i += 1024) {
        float4 v = rp4[i];
        const int base = i * 4;
        unsigned kk[4] = { mono(__float_as_uint(v.x)), mono(__float_as_uint(v.y)),
                           mono(__float_as_uint(v.z)), mono(__float_as_uint(v.w)) };
        #pragma unroll
        for (int c = 0; c < 4; ++c) {
            if ((kk[c] >> FB_SHIFT) >= tb) {
                unsigned p = atomicAdd(&ccount, 1u);
                if (p < FB_CAND)
                    cand[p] = ((unsigned long long)kk[c] << 32) | (unsigned)(~(base + c));
            }
        }
    }
    __syncthreads();
    for (int i = tid; i < FB_CAND; i += 1024)
        if ((unsigned)i >= ccount) cand[i] = 0ull;
    __syncthreads();
    for (int k = 2; k <= FB_CAND; k <<= 1) {
        for (int j = k >> 1; j > 0; j >>= 1) {
            for (int i = tid; i < FB_CAND; i += 1024) {
                int ixj = i ^ j;
                if (ixj > i) {
                    unsigned long long a = cand[i], b = cand[ixj];
                    bool sw = ((i & k) == 0) ? (a < b) : (a > b);
                    if (sw) { cand[i] = b; cand[ixj] = a; }
                }
            }
            __syncthreads();
        }
    }
    const float topk_f = params[row * 3 + 0];
    const float temp   = params[row * 3 + 2];
    if (tid < K) {
        unsigned long long c = cand[tid];
        float val = inv_mono((unsigned)(c >> 32));
        sidx[tid] = (int)(~(unsigned)c);
        float v = (((float)tid) >= topk_f) ? IGNORED_C : val;
        sv[tid] = v / temp;
    }
    __syncthreads();
    if (tid == 0) {
        float mm = sv[0];
        for (int i = 1; i < K; ++i) mm = fmaxf(mm, sv[i]);
        sred = mm;
    }
    __syncthreads();
    if (tid < K) se[tid] = expf(sv[tid] - sred);
    __syncthreads();
    if (tid == 0) {
        float s = 0.f;
        for (int i = 0; i < K; ++i) s += se[i];
        sred = s;
    }
    __syncthreads();
    if (tid < K) se[tid] = se[tid] / sred;
    __syncthreads();
    if (tid == 0) {
        float c = 0.f;
        for (int i = 0; i < K; ++i) { c += se[i]; se[i] = c; }
    }
    __syncthreads();
    if (tid < K) {
        ws_v[row * K + tid]    = sv[tid];
        ws_csum[row * K + tid] = se[tid];
        ws_idx[row * K + tid]  = sidx[tid];
    }
    if (tid == 0) ws_p0[row] = se[0];
}

extern "C" void kernel_launch(void* const* d_in, const int* in_sizes, int n_in,
                              void* d_out, int out_size, void* d_ws, size_t ws_size,
                              hipStream_t stream) {
    const float* logits = (const float*)d_in[0];
    const float* params = (const float*)d_in[1];
    const float* randu  = (const float*)d_in[2];
    int* out = (int*)d_out;
    char* ws = (char*)d_ws;

    const size_t cand_bytes = (size_t)BATCH * NCHUNK * K * 8;          // 4 MB
    const size_t tail_bytes = (size_t)3 * BATCH * K * 4 + BATCH * 4;   // 769 KB
    if (ws_size >= cand_bytes + tail_bytes) {
        unsigned long long* ws_cand = (unsigned long long*)ws;
        char* p = ws + cand_bytes;
        float* ws_v    = (float*)(p);
        float* ws_csum = (float*)(p + (size_t)BATCH * K * 4);
        int*   ws_idx  = (int*)  (p + (size_t)2 * BATCH * K * 4);
        float* ws_p0   = (float*)(p + (size_t)3 * BATCH * K * 4);
        hipLaunchKernelGGL(k1_topk_chunk, dim3(BATCH * NCHUNK), dim3(512), 0, stream,
                           logits, ws_cand);
        hipLaunchKernelGGL(k2_merge, dim3(BATCH), dim3(1024), 0, stream,
                           params, ws_cand, ws_v, ws_csum, ws_idx, ws_p0);
        hipLaunchKernelGGL(k3_sample, dim3(BATCH), dim3(K), 0, stream,
                           params, randu, ws_v, ws_csum, ws_idx, ws_p0, out);
    } else {
        float* ws_v    = (float*)(ws);
        float* ws_csum = (float*)(ws + (size_t)BATCH * K * 4);
        int*   ws_idx  = (int*)  (ws + (size_t)2 * BATCH * K * 4);
        float* ws_p0   = (float*)(ws + (size_t)3 * BATCH * K * 4);
        hipLaunchKernelGGL(fb_stage1, dim3(BATCH), dim3(1024), 0, stream,
                           logits, params, ws_v, ws_csum, ws_idx, ws_p0);
        hipLaunchKernelGGL(k3_sample, dim3(BATCH), dim3(K), 0, stream,
                           params, randu, ws_v, ws_csum, ws_idx, ws_p0, out);
    }
}

// Round 6
// 112.039 us; speedup vs baseline: 1.4547x; 1.1380x over previous
//
#include <hip/hip_runtime.h>
#include <hip/hip_bf16.h>

constexpr int BATCH = 256;
constexpr int VOCAB = 128000;
constexpr int K = 256;
constexpr float IGNORED_C = -3000.0f;

// fast path params
constexpr int NCHUNK = 8;
constexpr int CHUNK = VOCAB / NCHUNK;   // 16000
constexpr int CAP = 512;                // candidate cap == sort width == blockDim
constexpr int N4 = CHUNK / 4;           // 4000 float4 per chunk
constexpr int TAIL = N4 - 7 * 512;      // 416: threads with it==7 valid

// fallback path params
constexpr int FB_BINS = 8192;
constexpr int FB_SHIFT = 19;
constexpr int FB_CAND = 2048;

// order-preserving f32 -> u32 map (larger float => larger key)
__device__ __forceinline__ unsigned mono(unsigned u) {
    return (u & 0x80000000u) ? ~u : (u | 0x80000000u);
}
__device__ __forceinline__ float inv_mono(unsigned k) {
    unsigned u = (k & 0x80000000u) ? (k ^ 0x80000000u) : ~k;
    return __uint_as_float(u);
}

// ============================================================================
// K1: per (row, chunk) exact top-256 (value desc, idx asc), sorted, u64 keys.
// Selection: sampled threshold + exact register count passes.
// __launch_bounds__(512, 4): 128-VGPR budget so the 32-VGPR data array stays
// in registers (rounds 4/5 spilled under the 64-VGPR budget of (512, 8)).
// ============================================================================
__global__ __launch_bounds__(512, 4)
void k1_topk_chunk(const float* __restrict__ logits,
                   unsigned long long* __restrict__ ws_cand)
{
    __shared__ unsigned long long cand[CAP];
    __shared__ unsigned samp[512];
    __shared__ unsigned wred[16];
    __shared__ unsigned ccount;

    const int tid = threadIdx.x;
    const int wave = tid >> 6, lane = tid & 63;
    const int row = blockIdx.x >> 3;            // NCHUNK == 8
    const int chunk = blockIdx.x & 7;
    const int gbase = chunk * CHUNK;
    const float4* rp4 = reinterpret_cast<const float4*>(
        logits + (size_t)row * VOCAB + (size_t)gbase);

    // ---- load ~31 floats/thread as monotone keys (one HBM sweep) ----
    uint4 r[8];
    #pragma unroll
    for (int it = 0; it < 8; ++it) {
        const int i = tid + it * 512;
        if (it < 7 || tid < TAIL) {
            float4 f = rp4[i];
            r[it] = make_uint4(mono(__float_as_uint(f.x)), mono(__float_as_uint(f.y)),
                               mono(__float_as_uint(f.z)), mono(__float_as_uint(f.w)));
        } else {
            r[it] = make_uint4(0u, 0u, 0u, 0u);   // never counted (guarded)
        }
    }

    // ---- exact count pass over registers ----
    auto count_pass = [&](unsigned T, unsigned tieX, unsigned &ngt, unsigned &neq) {
        unsigned cgt = 0, ceq = 0;
        #pragma unroll
        for (int it = 0; it < 8; ++it) {
            if (it == 7 && tid >= TAIL) continue;
            const unsigned base = 4u * (unsigned)(tid + it * 512);
            const uint4 q = r[it];
            cgt += (q.x > T); ceq += (q.x == T && (base + 0u) <= tieX);
            cgt += (q.y > T); ceq += (q.y == T && (base + 1u) <= tieX);
            cgt += (q.z > T); ceq += (q.z == T && (base + 2u) <= tieX);
            cgt += (q.w > T); ceq += (q.w == T && (base + 3u) <= tieX);
        }
        #pragma unroll
        for (int off = 32; off >= 1; off >>= 1) {
            cgt += __shfl_xor(cgt, off);
            ceq += __shfl_xor(ceq, off);
        }
        __syncthreads();                 // protect wred reuse across passes
        if (lane == 0) { wred[wave] = cgt; wred[8 + wave] = ceq; }
        __syncthreads();
        unsigned g = 0, e = 0;
        #pragma unroll
        for (int w2 = 0; w2 < 8; ++w2) { g += wred[w2]; e += wred[8 + w2]; }
        ngt = g; neq = e;
    };

    // ---- sample: one key per thread (first quarter of chunk), sort desc ----
    {
        const int j2 = tid & 3, c = (tid >> 2) & 3;
        uint4 f = r[0];
        if (j2 == 1) f = r[1];
        if (j2 == 2) f = r[2];
        if (j2 == 3) f = r[3];
        unsigned sv = f.x;
        if (c == 1) sv = f.y;
        if (c == 2) sv = f.z;
        if (c == 3) sv = f.w;

        unsigned v = sv;
        #pragma unroll
        for (int kk = 2; kk <= 512; kk <<= 1) {
            for (int j = kk >> 1; j > 0; j >>= 1) {
                const bool keepMax = (((tid & kk) == 0) == ((tid & j) == 0));
                unsigned w;
                if (j >= 64) {
                    __syncthreads();
                    samp[tid] = v;
                    __syncthreads();
                    w = samp[tid ^ j];
                } else {
                    w = __shfl_xor(v, j);
                }
                v = keepMax ? (v >= w ? v : w) : (v <= w ? v : w);
            }
        }
        __syncthreads();
        samp[tid] = v;                   // sorted descending
        __syncthreads();
    }

    // ---- threshold: T = samp[11] (expected count ~375), verify exactly ----
    unsigned T = samp[11];
    unsigned ngt, neq;
    count_pass(T, 0xFFFFFFFFu, ngt, neq);
    unsigned nge = ngt + neq;

    if (nge < (unsigned)K || nge > (unsigned)CAP) {
        // rank-space binary search: smallest r with n_ge(samp[r]) >= K
        int lo, hi;
        if (nge < (unsigned)K) { lo = 11; hi = 511; }   // samp[511]: count>=512>=K
        else                   { lo = -1; hi = 11;  }   // samp[11] already >= K
        while (hi - lo > 1) {
            const int mid = (lo + hi) >> 1;
            count_pass(samp[mid], 0xFFFFFFFFu, ngt, neq);
            if (ngt + neq >= (unsigned)K) hi = mid; else lo = mid;
        }
        T = samp[hi];
        count_pass(T, 0xFFFFFFFFu, ngt, neq);
        nge = ngt + neq;
        if (nge > (unsigned)CAP) {
            // key-space: largest T0 with n_ge(T0) >= K in (samp[hi], khi]
            unsigned klo = T;
            unsigned khi = (hi > 0) ? samp[hi - 1] : 0xFFFFFFFFu;
            count_pass(khi, 0xFFFFFFFFu, ngt, neq);
            if (ngt + neq >= (unsigned)K) {
                klo = khi;
            } else {
                while (khi - klo > 1) {
                    const unsigned kmid = klo + ((khi - klo) >> 1);
                    count_pass(kmid, 0xFFFFFFFFu, ngt, neq);
                    if (ngt + neq >= (unsigned)K) klo = kmid; else khi = kmid;
                }
            }
            T = klo;
            count_pass(T, 0xFFFFFFFFu, ngt, neq);
            nge = ngt + neq;
        }
    }

    // ---- tie path (pathological duplicates): pick K-ngt smallest indices at T ----
    bool tie = false;
    unsigned X = 0xFFFFFFFFu;
    if (nge > (unsigned)CAP) {
        tie = true;
        const unsigned target = (unsigned)K - ngt;     // ngt < K by maximality of T
        int xlo = -1, xhi = CHUNK - 1;
        while (xhi - xlo > 1) {
            const int xmid = (xlo + xhi) >> 1;
            unsigned g2, e2;
            count_pass(T, (unsigned)xmid, g2, e2);
            if (e2 >= target) xhi = xmid; else xlo = xmid;
        }
        X = (unsigned)xhi;
    }

    // ---- collect candidates from registers ----
    if (tid == 0) ccount = 0u;
    __syncthreads();
    #pragma unroll
    for (int it = 0; it < 8; ++it) {
        if (it == 7 && tid >= TAIL) continue;
        const unsigned base = 4u * (unsigned)(tid + it * 512);
        const uint4 q = r[it];
        #pragma unroll
        for (int c = 0; c < 4; ++c) {
            const unsigned k2 = (c == 0) ? q.x : (c == 1) ? q.y : (c == 2) ? q.z : q.w;
            const unsigned loc = base + (unsigned)c;
            const bool sel = (k2 > T) || (k2 == T && (!tie || loc <= X));
            if (sel) {
                const unsigned p = atomicAdd(&ccount, 1u);
                if (p < (unsigned)CAP)
                    cand[p] = ((unsigned long long)k2 << 32) | (unsigned)(~(gbase + (int)loc));
            }
        }
    }
    __syncthreads();
    const unsigned cc = ccount;
    if ((unsigned)tid >= cc) cand[tid] = 0ull;   // pad (always < any candidate)
    __syncthreads();

    // ---- hybrid bitonic sort 512 candidates (u64), descending ----
    unsigned long long v = cand[tid];
    #pragma unroll
    for (int kk = 2; kk <= CAP; kk <<= 1) {
        for (int j = kk >> 1; j > 0; j >>= 1) {
            const bool keepMax = (((tid & kk) == 0) == ((tid & j) == 0));
            unsigned long long w;
            if (j >= 64) {
                __syncthreads();
                cand[tid] = v;
                __syncthreads();
                w = cand[tid ^ j];
            } else {
                w = __shfl_xor(v, j);
            }
            v = keepMax ? (v >= w ? v : w) : (v <= w ? v : w);
        }
    }

    if (tid < K) ws_cand[(size_t)blockIdx.x * K + tid] = v;
}

// ============================================================================
// K2: per row merge 8 sorted runs (bitonic merge stages only) + pipeline
// ============================================================================
__global__ __launch_bounds__(1024)
void k2_merge(const float* __restrict__ params,
              const unsigned long long* __restrict__ ws_cand,
              float* __restrict__ ws_v, float* __restrict__ ws_csum,
              int* __restrict__ ws_idx, float* __restrict__ ws_p0)
{
    constexpr int N = NCHUNK * K;   // 2048
    __shared__ unsigned long long cand[N];
    __shared__ float red[K];
    __shared__ float sc[K];

    const int row = blockIdx.x;
    const int tid = threadIdx.x;

    // load; reverse odd runs so runs alternate desc/asc (valid bitonic state k=256)
    for (int i = tid; i < N; i += 1024) {
        const int c = i >> 8, pos = i & (K - 1);
        unsigned long long v = ws_cand[(size_t)row * N + i];
        const int dest = (c & 1) ? ((c << 8) | (K - 1 - pos)) : i;
        cand[dest] = v;
    }
    __syncthreads();

    // bitonic merge stages k = 512, 1024, 2048 (descending overall)
    for (int kk2 = 2 * K; kk2 <= N; kk2 <<= 1) {
        for (int j = kk2 >> 1; j > 0; j >>= 1) {
            for (int i = tid; i < N; i += 1024) {
                const int ixj = i ^ j;
                if (ixj > i) {
                    unsigned long long a = cand[i], b = cand[ixj];
                    bool sw = ((i & kk2) == 0) ? (a < b) : (a > b);
                    if (sw) { cand[i] = b; cand[ixj] = a; }
                }
            }
            __syncthreads();
        }
    }

    // pipeline on top-256: topk-mask -> /temp -> softmax -> cumsum
    const bool act = tid < K;
    const float topk_f = params[row * 3 + 0];
    const float temp   = params[row * 3 + 2];
    float v = 0.f;
    int myidx = 0;
    if (act) {
        unsigned long long c = cand[tid];
        float val = inv_mono((unsigned)(c >> 32));
        myidx = (int)(~(unsigned)c);
        float x = (((float)tid) >= topk_f) ? IGNORED_C : val;
        v = x / temp;
        red[tid] = v;
    }
    __syncthreads();
    for (int s = K / 2; s > 0; s >>= 1) {
        if (tid < s) red[tid] = fmaxf(red[tid], red[tid + s]);
        __syncthreads();
    }
    const float m = red[0];
    __syncthreads();
    const float e = act ? expf(v - m) : 0.f;
    if (act) red[tid] = e;
    __syncthreads();
    for (int s = K / 2; s > 0; s >>= 1) {
        if (tid < s) red[tid] += red[tid + s];
        __syncthreads();
    }
    const float ssum = red[0];
    __syncthreads();
    const float p = e / ssum;
    if (act) sc[tid] = p;
    __syncthreads();
    for (int off = 1; off < K; off <<= 1) {
        float t = 0.f;
        if (act && tid >= off) t = sc[tid - off];
        __syncthreads();
        if (act) sc[tid] += t;
        __syncthreads();
    }
    if (act) {
        ws_v[row * K + tid]    = v;
        ws_csum[row * K + tid] = sc[tid];
        ws_idx[row * K + tid]  = myidx;
    }
    if (tid == 0) ws_p0[row] = p;   // probs[0] == csum[0]
}

// ============================================================================
// K3: global-min(p0) -> top-p mask -> softmax -> cumsum -> sample
// ============================================================================
__global__ __launch_bounds__(K)
void k3_sample(const float* __restrict__ params,
               const float* __restrict__ rand_u,
               const float* __restrict__ ws_v,
               const float* __restrict__ ws_csum,
               const int* __restrict__ ws_idx,
               const float* __restrict__ ws_p0,
               int* __restrict__ out)
{
    __shared__ float red[K];
    __shared__ float sc[K];
    const int row = blockIdx.x;
    const int tid = threadIdx.x;

    red[tid] = ws_p0[tid];          // BATCH == 256 == blockDim
    __syncthreads();
    for (int s = K / 2; s > 0; s >>= 1) {
        if (tid < s) red[tid] = fminf(red[tid], red[tid + s]);
        __syncthreads();
    }
    const float tpe = fmaxf(red[0], params[row * 3 + 1]);
    __syncthreads();

    const float csum = ws_csum[row * K + tid];
    const float v0   = ws_v[row * K + tid];
    const float v2 = ((csum > tpe) && (tid != 0)) ? IGNORED_C : v0;
    red[tid] = v2;
    __syncthreads();
    for (int s = K / 2; s > 0; s >>= 1) {
        if (tid < s) red[tid] = fmaxf(red[tid], red[tid + s]);
        __syncthreads();
    }
    const float m = red[0];
    __syncthreads();
    const float e = expf(v2 - m);
    red[tid] = e;
    __syncthreads();
    for (int s = K / 2; s > 0; s >>= 1) {
        if (tid < s) red[tid] += red[tid + s];
        __syncthreads();
    }
    const float ssum = red[0];
    __syncthreads();
    const float p = e / ssum;
    sc[tid] = p;
    __syncthreads();
    for (int off = 1; off < K; off <<= 1) {
        float t = (tid >= off) ? sc[tid - off] : 0.f;
        __syncthreads();
        sc[tid] += t;
        __syncthreads();
    }
    const float ru = rand_u[row];
    red[tid] = (ru > sc[tid]) ? 1.f : 0.f;
    __syncthreads();
    for (int s = K / 2; s > 0; s >>= 1) {
        if (tid < s) red[tid] += red[tid + s];
        __syncthreads();
    }
    if (tid == 0) {
        int sel = (int)red[0];
        if (sel > K - 1) sel = K - 1;
        out[row] = ws_idx[row * K + sel];
    }
}

// ============================================================================
// Fallback (round-1 proven): single block per row, used only if ws too small
// ============================================================================
__global__ __launch_bounds__(1024)
void fb_stage1(const float* __restrict__ logits,
               const float* __restrict__ params,
               float* __restrict__ ws_v,
               float* __restrict__ ws_csum,
               int* __restrict__ ws_idx,
               float* __restrict__ ws_p0)
{
    __shared__ unsigned hist[FB_BINS];
    __shared__ unsigned gsum[128];
    __shared__ unsigned long long cand[FB_CAND];
    __shared__ unsigned ccount;
    __shared__ int tbin;
    __shared__ float sv[K];
    __shared__ float se[K];
    __shared__ int   sidx[K];
    __shared__ float sred;

    const int row = blockIdx.x;
    const int tid = threadIdx.x;
    const float4* rp4 = reinterpret_cast<const float4*>(logits + (size_t)row * VOCAB);

    for (int i = tid; i < FB_BINS; i += 1024) hist[i] = 0u;
    __syncthreads();
    for (int i = tid; i < VOCAB / 4; i += 1024) {
        float4 v = rp4[i];
        atomicAdd(&hist[mono(__float_as_uint(v.x)) >> FB_SHIFT], 1u);
        atomicAdd(&hist[mono(__float_as_uint(v.y)) >> FB_SHIFT], 1u);
        atomicAdd(&hist[mono(__float_as_uint(v.z)) >> FB_SHIFT], 1u);
        atomicAdd(&hist[mono(__float_as_uint(v.w)) >> FB_SHIFT], 1u);
    }
    __syncthreads();
    if (tid < 128) {
        unsigned s = 0;
        for (int i = 0; i < 64; ++i) s += hist[tid * 64 + i];
        gsum[tid] = s;
    }
    __syncthreads();
    if (tid == 0) {
        unsigned acc = 0;
        int g = 127;
        for (; g > 0; --g) {
            if (acc + gsum[g] >= (unsigned)K) break;
            acc += gsum[g];
        }
        int t = g * 64;
        for (int bin = g * 64 + 63; bin >= g * 64; --bin) {
            acc += hist[bin];
            if (acc >= (unsigned)K) { t = bin; break; }
        }
        tbin = t;
        ccount = 0u;
    }
    __syncthreads();
    const unsigned tb = (unsigned)tbin;
    for (int i = tid; i < VOCAB / 4; i += 1024) {
        float4 v = rp4[i];
        const int base = i * 4;
        unsigned kk[4] = { mono(__float_as_uint(v.x)), mono(__float_as_uint(v.y)),
                           mono(__float_as_uint(v.z)), mono(__float_as_uint(v.w)) };
        #pragma unroll
        for (int c = 0; c < 4; ++c) {
            if ((kk[c] >> FB_SHIFT) >= tb) {
                unsigned p = atomicAdd(&ccount, 1u);
                if (p < FB_CAND)
                    cand[p] = ((unsigned long long)kk[c] << 32) | (unsigned)(~(base + c));
            }
        }
    }
    __syncthreads();
    for (int i = tid; i < FB_CAND; i += 1024)
        if ((unsigned)i >= ccount) cand[i] = 0ull;
    __syncthreads();
    for (int k = 2; k <= FB_CAND; k <<= 1) {
        for (int j = k >> 1; j > 0; j >>= 1) {
            for (int i = tid; i < FB_CAND; i += 1024) {
                int ixj = i ^ j;
                if (ixj > i) {
                    unsigned long long a = cand[i], b = cand[ixj];
                    bool sw = ((i & k) == 0) ? (a < b) : (a > b);
                    if (sw) { cand[i] = b; cand[ixj] = a; }
                }
            }
            __syncthreads();
        }
    }
    const float topk_f = params[row * 3 + 0];
    const float temp   = params[row * 3 + 2];
    if (tid < K) {
        unsigned long long c = cand[tid];
        float val = inv_mono((unsigned)(c >> 32));
        sidx[tid] = (int)(~(unsigned)c);
        float v = (((float)tid) >= topk_f) ? IGNORED_C : val;
        sv[tid] = v / temp;
    }
    __syncthreads();
    if (tid == 0) {
        float mm = sv[0];
        for (int i = 1; i < K; ++i) mm = fmaxf(mm, sv[i]);
        sred = mm;
    }
    __syncthreads();
    if (tid < K) se[tid] = expf(sv[tid] - sred);
    __syncthreads();
    if (tid == 0) {
        float s = 0.f;
        for (int i = 0; i < K; ++i) s += se[i];
        sred = s;
    }
    __syncthreads();
    if (tid < K) se[tid] = se[tid] / sred;
    __syncthreads();
    if (tid == 0) {
        float c = 0.f;
        for (int i = 0; i < K; ++i) { c += se[i]; se[i] = c; }
    }
    __syncthreads();
    if (tid < K) {
        ws_v[row * K + tid]    = sv[tid];
        ws_csum[row * K + tid] = se[tid];
        ws_idx[row * K + tid]  = sidx[tid];
    }
    if (tid == 0) ws_p0[row] = se[0];
}

extern "C" void kernel_launch(void* const* d_in, const int* in_sizes, int n_in,
                              void* d_out, int out_size, void* d_ws, size_t ws_size,
                              hipStream_t stream) {
    const float* logits = (const float*)d_in[0];
    const float* params = (const float*)d_in[1];
    const float* randu  = (const float*)d_in[2];
    int* out = (int*)d_out;
    char* ws = (char*)d_ws;

    const size_t cand_bytes = (size_t)BATCH * NCHUNK * K * 8;          // 4 MB
    const size_t tail_bytes = (size_t)3 * BATCH * K * 4 + BATCH * 4;   // 769 KB
    if (ws_size >= cand_bytes + tail_bytes) {
        unsigned long long* ws_cand = (unsigned long long*)ws;
        char* p = ws + cand_bytes;
        float* ws_v    = (float*)(p);
        float* ws_csum = (float*)(p + (size_t)BATCH * K * 4);
        int*   ws_idx  = (int*)  (p + (size_t)2 * BATCH * K * 4);
        float* ws_p0   = (float*)(p + (size_t)3 * BATCH * K * 4);
        hipLaunchKernelGGL(k1_topk_chunk, dim3(BATCH * NCHUNK), dim3(512), 0, stream,
                           logits, ws_cand);
        hipLaunchKernelGGL(k2_merge, dim3(BATCH), dim3(1024), 0, stream,
                           params, ws_cand, ws_v, ws_csum, ws_idx, ws_p0);
        hipLaunchKernelGGL(k3_sample, dim3(BATCH), dim3(K), 0, stream,
                           params, randu, ws_v, ws_csum, ws_idx, ws_p0, out);
    } else {
        float* ws_v    = (float*)(ws);
        float* ws_csum = (float*)(ws + (size_t)BATCH * K * 4);
        int*   ws_idx  = (int*)  (ws + (size_t)2 * BATCH * K * 4);
        float* ws_p0   = (float*)(ws + (size_t)3 * BATCH * K * 4);
        hipLaunchKernelGGL(fb_stage1, dim3(BATCH), dim3(1024), 0, stream,
                           logits, params, ws_v, ws_csum, ws_idx, ws_p0);
        hipLaunchKernelGGL(k3_sample, dim3(BATCH), dim3(K), 0, stream,
                           params, randu, ws_v, ws_csum, ws_idx, ws_p0, out);
    }
}